// Round 5
// baseline (246.439 us; speedup 1.0000x reference)
//
#include <hip/hip_runtime.h>

#define DEV static __device__ __forceinline__

typedef __attribute__((ext_vector_type(8))) short short8;
typedef __attribute__((ext_vector_type(8))) __bf16 bf16x8;
typedef __attribute__((ext_vector_type(4))) float f32x4;

// N=8 agents, B=8192, OBS=128, ACT=32, D=160, E=128, L=8
//
// pi-layout: within each 128-wide k-chunk, position p = 8*g + m holds actual
// k = 16*m + g. Applied consistently to eB, SB, WvP, W1P so MFMA operand
// elements pair correctly; benefit: a lane's 8 C-layout accumulator values
// (cols 16m+lr, m=0..7) form one contiguous 16B granule at (row, granule=lr).

DEV short f2bf(float f) { return __builtin_bit_cast(short, (__bf16)f); }
DEV float bf2f(short h) {
  unsigned u = ((unsigned)(unsigned short)h) << 16;
  return __builtin_bit_cast(float, u);
}
DEV f32x4 mfma16(short8 a, short8 b, f32x4 c) {
  return __builtin_amdgcn_mfma_f32_16x16x32_bf16(
      __builtin_bit_cast(bf16x8, a), __builtin_bit_cast(bf16x8, b), c, 0, 0, 0);
}
DEV void async_copy16(short* lds, const short* g) {
  __builtin_amdgcn_global_load_lds(
      (const __attribute__((address_space(1))) void*)g,
      (__attribute__((address_space(3))) void*)lds, 16, 0, 0);
}

template <int GPC, int SRC_STRIDE, int LDS_STRIDE>
DEV void stage_bt(short* lds, const short* src, int tid) {
  constexpr int TOTAL = 128 * GPC;
  #pragma unroll
  for (int g0 = 0; g0 < TOTAL; g0 += 256) {
    int g = g0 + tid;
    int c = g / GPC, kg = g % GPC;
    *(short8*)(lds + c * LDS_STRIDE + kg * 8) =
        *(const short8*)(src + c * SRC_STRIDE + kg * 8);
  }
}

// ---- K0: weights fp32 [K][128] -> bf16 [128][K]; Wv/W1 in pi-k order -------
__global__ __launch_bounds__(256) void k0_tr(const float* __restrict__ Wg,
                                             const float* __restrict__ Wv,
                                             const float* __restrict__ W1,
                                             short* __restrict__ WgT,
                                             short* __restrict__ WvP,
                                             short* __restrict__ W1P) {
  int g = blockIdx.x * 256 + threadIdx.x;  // 184320 granules total
  short8 o;
  if (g < 20480) {  // Wg: 8 x 128c x 20g, K=160, natural k
    int n = g / 2560, rem = g % 2560;
    int c = rem / 20, kg = rem % 20;
    const float* src = Wg + n * 20480;
    #pragma unroll
    for (int j = 0; j < 8; ++j) o[j] = f2bf(src[(size_t)(kg * 8 + j) * 128 + c]);
    *(short8*)(WgT + n * 20480 + c * 160 + kg * 8) = o;
  } else if (g < 36864) {  // Wv: 8 x 128c x 16g, K=128, pi order
    int g2 = g - 20480;
    int n = g2 / 2048, rem = g2 % 2048;
    int c = rem / 16, kg = rem % 16;
    const float* src = Wv + n * 16384;
    #pragma unroll
    for (int j = 0; j < 8; ++j) o[j] = f2bf(src[(size_t)(16 * j + kg) * 128 + c]);
    *(short8*)(WvP + n * 16384 + c * 128 + kg * 8) = o;
  } else {  // W1: 8 x 128c x 144g, K=1152, pi order within each 128-chunk
    int g3 = g - 36864;
    int n = g3 / 18432, rem = g3 % 18432;
    int c = rem / 144, kg = rem % 144;
    int chunk = kg >> 4, kl = kg & 15;
    const float* src = W1 + (size_t)n * 147456;
    #pragma unroll
    for (int j = 0; j < 8; ++j)
      o[j] = f2bf(src[(size_t)(chunk * 128 + 16 * j + kl) * 128 + c]);
    *(short8*)(W1P + (size_t)n * 147456 + c * 1152 + kg * 8) = o;
  }
}

// ---- K1: e = relu(oa @ Wg + bg) -> bf16, pi-packed granule stores ----------
__global__ __launch_bounds__(256) void k1_e(const float* __restrict__ obs,
                                            const float* __restrict__ act,
                                            const short* __restrict__ WgT,
                                            const float* __restrict__ bg,
                                            short* __restrict__ eB) {
  __shared__ __align__(16) short BW[128 * 168];
  const int btile = blockIdx.x, n = blockIdx.y, tid = threadIdx.x;
  stage_bt<20, 160, 168>(BW, WgT + n * 20480, tid);
  __syncthreads();
  const int lane = tid & 63, wave = tid >> 6, lr = lane & 15, kg = lane >> 4;
  const int rowbase = btile * 64 + wave * 16;
  f32x4 acc[8];
  #pragma unroll
  for (int m = 0; m < 8; ++m) acc[m] = f32x4{0.f, 0.f, 0.f, 0.f};
  const float* obsp = obs + (size_t)(n * 8192 + rowbase + lr) * 128;
  const float* actp = act + (size_t)(n * 8192 + rowbase + lr) * 32;
  #pragma unroll
  for (int ks = 0; ks < 5; ++ks) {
    const float* ap = (ks < 4) ? (obsp + ks * 32 + kg * 8) : (actp + kg * 8);
    float4 p0 = *(const float4*)ap;
    float4 p1 = *(const float4*)(ap + 4);
    short8 a;
    a[0] = f2bf(p0.x); a[1] = f2bf(p0.y); a[2] = f2bf(p0.z); a[3] = f2bf(p0.w);
    a[4] = f2bf(p1.x); a[5] = f2bf(p1.y); a[6] = f2bf(p1.z); a[7] = f2bf(p1.w);
    #pragma unroll
    for (int m = 0; m < 8; ++m) {
      short8 b = *(const short8*)(&BW[(m * 16 + lr) * 168 + ks * 32 + kg * 8]);
      acc[m] = mfma16(a, b, acc[m]);
    }
  }
  float bgv[8];
  #pragma unroll
  for (int m = 0; m < 8; ++m) bgv[m] = bg[n * 128 + m * 16 + lr];
  #pragma unroll
  for (int r = 0; r < 4; ++r) {
    short8 pkt;
    #pragma unroll
    for (int m = 0; m < 8; ++m) {
      float x = acc[m][r] + bgv[m];
      pkt[m] = f2bf(x > 0.f ? x : 0.f);
    }
    *(short8*)(eB + (size_t)(n * 8192 + rowbase + kg * 4 + r) * 128 + lr * 8) = pkt;
  }
}

// ---- K2: S[l] = sum_j leaky(e[j] @ Wv[l] + bv[l]) -> bf16, pi-packed -------
__global__ __launch_bounds__(256) void k2_S(const short* __restrict__ eB,
                                            const short* __restrict__ WvP,
                                            const float* __restrict__ bv,
                                            short* __restrict__ SB) {
  __shared__ __align__(16) short BW[128 * 136];
  const int btile = blockIdx.x, l = blockIdx.y, tid = threadIdx.x;
  stage_bt<16, 128, 136>(BW, WvP + l * 16384, tid);
  __syncthreads();
  const int lane = tid & 63, wave = tid >> 6, lr = lane & 15, kg = lane >> 4;
  const int rowbase = btile * 64 + wave * 16;
  f32x4 Sacc[8];
  #pragma unroll
  for (int m = 0; m < 8; ++m) Sacc[m] = f32x4{0.f, 0.f, 0.f, 0.f};
  float bvv[8];
  #pragma unroll
  for (int m = 0; m < 8; ++m) bvv[m] = bv[l * 128 + m * 16 + lr];
  for (int j = 0; j < 8; ++j) {
    f32x4 acc[8];
    #pragma unroll
    for (int m = 0; m < 8; ++m) acc[m] = f32x4{0.f, 0.f, 0.f, 0.f};
    const short* ep = eB + (size_t)(j * 8192 + rowbase + lr) * 128;
    #pragma unroll
    for (int ks = 0; ks < 4; ++ks) {
      short8 a = *(const short8*)(ep + ks * 32 + kg * 8);
      #pragma unroll
      for (int m = 0; m < 8; ++m) {
        short8 b = *(const short8*)(&BW[(m * 16 + lr) * 136 + ks * 32 + kg * 8]);
        acc[m] = mfma16(a, b, acc[m]);
      }
    }
    #pragma unroll
    for (int m = 0; m < 8; ++m)
      #pragma unroll
      for (int r = 0; r < 4; ++r) {
        float x = acc[m][r] + bvv[m];
        Sacc[m][r] += (x > 0.f ? x : 0.01f * x);
      }
  }
  #pragma unroll
  for (int r = 0; r < 4; ++r) {
    short8 pkt;
    #pragma unroll
    for (int m = 0; m < 8; ++m) pkt[m] = f2bf(Sacc[m][r]);
    *(short8*)(SB + (size_t)(l * 8192 + rowbase + kg * 4 + r) * 128 + lr * 8) = pkt;
  }
}

// ---- K3: fused 17-chunk GEMM, 256 rows/block, 8 waves, agent->XCD pinned.
//      h = relu(sum_l (S_l - v_{l,i})@W1_l + e@W1e + b1); out = h.W2 + b2.
//      v recomputed in-kernel; C->A via per-wave 2KB VB round-trip (2 halves);
//      SB operand prefetched one head ahead in registers.
__global__ __launch_bounds__(512) void k3_f(const short* __restrict__ eB,
                                            const short* __restrict__ SB,
                                            const short* __restrict__ WvP,
                                            const short* __restrict__ W1P,
                                            const float* __restrict__ bv,
                                            const float* __restrict__ b1,
                                            const float* __restrict__ W2,
                                            const float* __restrict__ b2,
                                            float* __restrict__ out) {
  __shared__ __align__(16) short BW[2][128 * 128];  // 64 KB dbuf
  __shared__ __align__(16) short VB[8][8 * 128];    // 16 KB, per-wave half-slices
  const int bid = blockIdx.x;
  const int i = bid & 7;        // agent -> XCD pinning (round-robin dispatch)
  const int btile = bid >> 3;   // 32 btiles x 256 rows
  const int tid = threadIdx.x;
  const int lane = tid & 63, wave = tid >> 6, lr = lane & 15, kg = lane >> 4;
  const int lr8 = lane & 7;
  const int rowbase = btile * 256 + wave * 32;
  const short* w1 = W1P + (size_t)i * 147456;
  short* vb = VB[wave];

#define STAGE_WV(buf, l)                                                       \
  {                                                                            \
    _Pragma("unroll") for (int t = 0; t < 4; ++t) {                            \
      int G = t * 512 + tid;                                                   \
      int cG = G >> 4, gl = G & 15;                                            \
      async_copy16((buf) + (t * 512 + wave * 64) * 8,                          \
                   WvP + (l) * 16384 + cG * 128 + ((gl ^ (cG & 7)) << 3));     \
    }                                                                          \
  }
#define STAGE_W1(buf, koff)                                                    \
  {                                                                            \
    _Pragma("unroll") for (int t = 0; t < 4; ++t) {                            \
      int G = t * 512 + tid;                                                   \
      int cG = G >> 4, gl = G & 15;                                            \
      async_copy16((buf) + (t * 512 + wave * 64) * 8,                          \
                   w1 + cG * 1152 + (koff) + ((gl ^ (cG & 7)) << 3));          \
    }                                                                          \
  }

  short8 ea[2][4];
  #pragma unroll
  for (int s = 0; s < 2; ++s)
    #pragma unroll
    for (int ks = 0; ks < 4; ++ks)
      ea[s][ks] = *(const short8*)(
          eB + (size_t)(i * 8192 + rowbase + s * 16 + lr) * 128 + (ks * 4 + kg) * 8);

  // SB prefetch registers (head l=0 loaded in prologue)
  short8 svp[2][4];
  #pragma unroll
  for (int s = 0; s < 2; ++s)
    #pragma unroll
    for (int r = 0; r < 4; ++r)
      svp[s][r] = *(const short8*)(
          SB + (size_t)(rowbase + s * 16 + kg * 4 + r) * 128 + lr * 8);

  f32x4 hacc[2][8];
  #pragma unroll
  for (int s = 0; s < 2; ++s)
    #pragma unroll
    for (int m = 0; m < 8; ++m) hacc[s][m] = f32x4{0.f, 0.f, 0.f, 0.f};
  short8 aa[2][4];

  STAGE_WV(BW[0], 0);
  for (int c = 0; c < 17; ++c) {
    __syncthreads();  // stage(c) drained; BW[(c+1)&1] free
    if (c < 16) {
      int nc = c + 1;
      if (nc == 16) { STAGE_W1(BW[0], 1024); }
      else if (nc & 1) { STAGE_W1(BW[1], (nc >> 1) * 128); }
      else { STAGE_WV(BW[0], nc >> 1); }
    }
    const short* bw = BW[c & 1];
    if (c == 16) {  // + e @ W1e
      #pragma unroll
      for (int ks = 0; ks < 4; ++ks)
        #pragma unroll
        for (int m = 0; m < 8; ++m) {
          short8 b = *(const short8*)(bw + (m * 16 + lr) * 128 +
                                      (((ks * 4 + kg) ^ lr8) << 3));
          hacc[0][m] = mfma16(ea[0][ks], b, hacc[0][m]);
          hacc[1][m] = mfma16(ea[1][ks], b, hacc[1][m]);
        }
    } else if (c & 1) {  // W1_l: hacc += (S-v) @ W1_l
      #pragma unroll
      for (int ks = 0; ks < 4; ++ks)
        #pragma unroll
        for (int m = 0; m < 8; ++m) {
          short8 b = *(const short8*)(bw + (m * 16 + lr) * 128 +
                                      (((ks * 4 + kg) ^ lr8) << 3));
          hacc[0][m] = mfma16(aa[0][ks], b, hacc[0][m]);
          hacc[1][m] = mfma16(aa[1][ks], b, hacc[1][m]);
        }
    } else {  // Wv_l: aa = S_l - leaky(e @ Wv_l + bv_l), via VB round-trip
      const int l = c >> 1;
      float bvv[8];
      #pragma unroll
      for (int m = 0; m < 8; ++m) bvv[m] = bv[l * 128 + m * 16 + lr];
      #pragma unroll
      for (int s = 0; s < 2; ++s) {
        f32x4 vacc[8];
        #pragma unroll
        for (int m = 0; m < 8; ++m) vacc[m] = f32x4{0.f, 0.f, 0.f, 0.f};
        #pragma unroll
        for (int ks = 0; ks < 4; ++ks)
          #pragma unroll
          for (int m = 0; m < 8; ++m) {
            short8 b = *(const short8*)(bw + (m * 16 + lr) * 128 +
                                        (((ks * 4 + kg) ^ lr8) << 3));
            vacc[m] = mfma16(ea[s][ks], b, vacc[m]);
          }
        short8 pkt[4];
        #pragma unroll
        for (int r = 0; r < 4; ++r)
          #pragma unroll
          for (int m = 0; m < 8; ++m) {
            float x = vacc[m][r] + bvv[m];
            x = (x > 0.f) ? x : 0.01f * x;   // leaky_relu
            pkt[r][m] = f2bf(bf2f(svp[s][r][m]) - x);
          }
        // C->A via 2KB/wave VB in two row-halves (exec-masked):
        // half p: lanes kg in {2p,2p+1} write local rows [0,8); lanes with
        // lr in [8p,8p+8) read their 4 A-fragments. Same-wave DS ordering
        // (compiler lgkmcnt) keeps write->read and half-reuse safe.
        #pragma unroll
        for (int p = 0; p < 2; ++p) {
          if ((kg >> 1) == p) {
            #pragma unroll
            for (int r = 0; r < 4; ++r) {
              int rl = (kg & 1) * 4 + r;
              *(short8*)(vb + rl * 128 + ((lr ^ rl) << 3)) = pkt[r];
            }
          }
          if ((lr >> 3) == p) {
            int rl = lr & 7;
            #pragma unroll
            for (int ks = 0; ks < 4; ++ks)
              aa[s][ks] = *(const short8*)(vb + rl * 128 +
                                           (((ks * 4 + kg) ^ rl) << 3));
          }
        }
      }
      // prefetch next head's SB operand (consumed at chunk c+2)
      if (l < 7) {
        #pragma unroll
        for (int s = 0; s < 2; ++s)
          #pragma unroll
          for (int r = 0; r < 4; ++r)
            svp[s][r] = *(const short8*)(
                SB + (size_t)((l + 1) * 8192 + rowbase + s * 16 + kg * 4 + r) * 128 +
                lr * 8);
      }
    }
  }
#undef STAGE_WV
#undef STAGE_W1

  // epilogue: h = relu(hacc + b1); out = h . W2 + b2
  #pragma unroll
  for (int s = 0; s < 2; ++s) {
    float sacc[4] = {0.f, 0.f, 0.f, 0.f};
    #pragma unroll
    for (int m = 0; m < 8; ++m) {
      int col = m * 16 + lr;
      float b1v = b1[i * 128 + col];
      float w2v = W2[i * 128 + col];
      #pragma unroll
      for (int r = 0; r < 4; ++r) {
        float h = hacc[s][m][r] + b1v;
        h = h > 0.f ? h : 0.f;
        sacc[r] += h * w2v;
      }
    }
    #pragma unroll
    for (int r = 0; r < 4; ++r) {
      float v = sacc[r];
      v += __shfl_xor(v, 1);
      v += __shfl_xor(v, 2);
      v += __shfl_xor(v, 4);
      v += __shfl_xor(v, 8);
      if (lr == 0)
        out[i * 8192 + rowbase + s * 16 + kg * 4 + r] = v + b2[i];
    }
  }
}

extern "C" void kernel_launch(void* const* d_in, const int* in_sizes, int n_in,
                              void* d_out, int out_size, void* d_ws, size_t ws_size,
                              hipStream_t stream) {
  const float* obs = (const float*)d_in[0];
  const float* act = (const float*)d_in[1];
  const float* Wg  = (const float*)d_in[2];
  const float* bg  = (const float*)d_in[3];
  // d_in[4..7] = Wq,bq,Wk,bk: dead (softmax over singleton axis == 1)
  const float* Wv  = (const float*)d_in[8];
  const float* bv  = (const float*)d_in[9];
  const float* W1  = (const float*)d_in[10];
  const float* b1  = (const float*)d_in[11];
  const float* W2  = (const float*)d_in[12];
  const float* b2  = (const float*)d_in[13];
  float* out = (float*)d_out;

  // workspace (bf16 shorts): eB 8.4M, SB 8.4M, WgT 163840, WvP 131072, W1P 1179648
  short* eB  = (short*)d_ws;
  short* SB  = eB + (size_t)8 * 8192 * 128;
  short* WgT = SB + (size_t)8 * 8192 * 128;
  short* WvP = WgT + 163840;
  short* W1P = WvP + 131072;

  k0_tr<<<720, 256, 0, stream>>>(Wg, Wv, W1, WgT, WvP, W1P);
  k1_e<<<dim3(128, 8), 256, 0, stream>>>(obs, act, WgT, bg, eB);
  k2_S<<<dim3(128, 8), 256, 0, stream>>>(eB, WvP, bv, SB);
  k3_f<<<256, 512, 0, stream>>>(eB, SB, WvP, W1P, bv, b1, W2, b2, out);
}

// Round 6
// 242.493 us; speedup vs baseline: 1.0163x; 1.0163x over previous
//
#include <hip/hip_runtime.h>

#define DEV static __device__ __forceinline__

typedef __attribute__((ext_vector_type(8))) short short8;
typedef __attribute__((ext_vector_type(8))) __bf16 bf16x8;
typedef __attribute__((ext_vector_type(4))) float f32x4;

// N=8 agents, B=8192, OBS=128, ACT=32, D=160, E=128, L=8
//
// pi-layout: within each 128-wide k-chunk, position p = 8*g + m holds actual
// k = 16*m + g. Applied consistently to eB, SB, WvP, W1P so MFMA operand
// elements pair correctly; benefit: a lane's 8 C-layout accumulator values
// (cols 16m+lr, m=0..7) form one contiguous 16B granule at (row, granule=lr).

DEV short f2bf(float f) { return __builtin_bit_cast(short, (__bf16)f); }
DEV float bf2f(short h) {
  unsigned u = ((unsigned)(unsigned short)h) << 16;
  return __builtin_bit_cast(float, u);
}
DEV f32x4 mfma16(short8 a, short8 b, f32x4 c) {
  return __builtin_amdgcn_mfma_f32_16x16x32_bf16(
      __builtin_bit_cast(bf16x8, a), __builtin_bit_cast(bf16x8, b), c, 0, 0, 0);
}
DEV void async_copy16(short* lds, const short* g) {
  __builtin_amdgcn_global_load_lds(
      (const __attribute__((address_space(1))) void*)g,
      (__attribute__((address_space(3))) void*)lds, 16, 0, 0);
}

template <int GPC, int SRC_STRIDE, int LDS_STRIDE>
DEV void stage_bt(short* lds, const short* src, int tid) {
  constexpr int TOTAL = 128 * GPC;
  #pragma unroll
  for (int g0 = 0; g0 < TOTAL; g0 += 256) {
    int g = g0 + tid;
    int c = g / GPC, kg = g % GPC;
    *(short8*)(lds + c * LDS_STRIDE + kg * 8) =
        *(const short8*)(src + c * SRC_STRIDE + kg * 8);
  }
}

// ---- K0: weights fp32 [K][128] -> bf16 [128][K]; Wv/W1 in pi-k order.
//      c-fastest lane mapping so the fp32 source reads coalesce. ------------
__global__ __launch_bounds__(256) void k0_tr(const float* __restrict__ Wg,
                                             const float* __restrict__ Wv,
                                             const float* __restrict__ W1,
                                             short* __restrict__ WgT,
                                             short* __restrict__ WvP,
                                             short* __restrict__ W1P) {
  int g = blockIdx.x * 256 + threadIdx.x;  // 184320 granules total
  short8 o;
  if (g < 20480) {  // Wg: 8 x 20kg x 128c, K=160, natural k
    int n = g / 2560, rem = g % 2560;
    int c = rem & 127, kg = rem >> 7;
    const float* src = Wg + n * 20480;
    #pragma unroll
    for (int j = 0; j < 8; ++j) o[j] = f2bf(src[(size_t)(kg * 8 + j) * 128 + c]);
    *(short8*)(WgT + n * 20480 + c * 160 + kg * 8) = o;
  } else if (g < 36864) {  // Wv: 8 x 16kg x 128c, K=128, pi order
    int g2 = g - 20480;
    int n = g2 >> 11, rem = g2 & 2047;
    int c = rem & 127, kg = rem >> 7;
    const float* src = Wv + n * 16384;
    #pragma unroll
    for (int j = 0; j < 8; ++j) o[j] = f2bf(src[(size_t)(16 * j + kg) * 128 + c]);
    *(short8*)(WvP + n * 16384 + c * 128 + kg * 8) = o;
  } else {  // W1: 8 x 144kg x 128c, K=1152, pi order within each 128-chunk
    int g3 = g - 36864;
    int n = g3 / 18432, rem = g3 % 18432;
    int c = rem & 127, kg = rem >> 7;
    int chunk = kg >> 4, kl = kg & 15;
    const float* src = W1 + (size_t)n * 147456;
    #pragma unroll
    for (int j = 0; j < 8; ++j)
      o[j] = f2bf(src[(size_t)(chunk * 128 + 16 * j + kl) * 128 + c]);
    *(short8*)(W1P + (size_t)n * 147456 + c * 1152 + kg * 8) = o;
  }
}

// ---- K1: e = relu(oa @ Wg + bg) -> bf16, pi-packed granule stores ----------
__global__ __launch_bounds__(256) void k1_e(const float* __restrict__ obs,
                                            const float* __restrict__ act,
                                            const short* __restrict__ WgT,
                                            const float* __restrict__ bg,
                                            short* __restrict__ eB) {
  __shared__ __align__(16) short BW[128 * 168];
  const int btile = blockIdx.x, n = blockIdx.y, tid = threadIdx.x;
  stage_bt<20, 160, 168>(BW, WgT + n * 20480, tid);
  __syncthreads();
  const int lane = tid & 63, wave = tid >> 6, lr = lane & 15, kg = lane >> 4;
  const int rowbase = btile * 64 + wave * 16;
  f32x4 acc[8];
  #pragma unroll
  for (int m = 0; m < 8; ++m) acc[m] = f32x4{0.f, 0.f, 0.f, 0.f};
  const float* obsp = obs + (size_t)(n * 8192 + rowbase + lr) * 128;
  const float* actp = act + (size_t)(n * 8192 + rowbase + lr) * 32;
  #pragma unroll
  for (int ks = 0; ks < 5; ++ks) {
    const float* ap = (ks < 4) ? (obsp + ks * 32 + kg * 8) : (actp + kg * 8);
    float4 p0 = *(const float4*)ap;
    float4 p1 = *(const float4*)(ap + 4);
    short8 a;
    a[0] = f2bf(p0.x); a[1] = f2bf(p0.y); a[2] = f2bf(p0.z); a[3] = f2bf(p0.w);
    a[4] = f2bf(p1.x); a[5] = f2bf(p1.y); a[6] = f2bf(p1.z); a[7] = f2bf(p1.w);
    #pragma unroll
    for (int m = 0; m < 8; ++m) {
      short8 b = *(const short8*)(&BW[(m * 16 + lr) * 168 + ks * 32 + kg * 8]);
      acc[m] = mfma16(a, b, acc[m]);
    }
  }
  float bgv[8];
  #pragma unroll
  for (int m = 0; m < 8; ++m) bgv[m] = bg[n * 128 + m * 16 + lr];
  #pragma unroll
  for (int r = 0; r < 4; ++r) {
    short8 pkt;
    #pragma unroll
    for (int m = 0; m < 8; ++m) {
      float x = acc[m][r] + bgv[m];
      pkt[m] = f2bf(x > 0.f ? x : 0.f);
    }
    *(short8*)(eB + (size_t)(n * 8192 + rowbase + kg * 4 + r) * 128 + lr * 8) = pkt;
  }
}

// ---- K2: S[l] = sum_j leaky(e[j] @ Wv[l] + bv[l]) -> bf16, pi-packed -------
__global__ __launch_bounds__(256) void k2_S(const short* __restrict__ eB,
                                            const short* __restrict__ WvP,
                                            const float* __restrict__ bv,
                                            short* __restrict__ SB) {
  __shared__ __align__(16) short BW[128 * 136];
  const int btile = blockIdx.x, l = blockIdx.y, tid = threadIdx.x;
  stage_bt<16, 128, 136>(BW, WvP + l * 16384, tid);
  __syncthreads();
  const int lane = tid & 63, wave = tid >> 6, lr = lane & 15, kg = lane >> 4;
  const int rowbase = btile * 64 + wave * 16;
  f32x4 Sacc[8];
  #pragma unroll
  for (int m = 0; m < 8; ++m) Sacc[m] = f32x4{0.f, 0.f, 0.f, 0.f};
  float bvv[8];
  #pragma unroll
  for (int m = 0; m < 8; ++m) bvv[m] = bv[l * 128 + m * 16 + lr];
  for (int j = 0; j < 8; ++j) {
    f32x4 acc[8];
    #pragma unroll
    for (int m = 0; m < 8; ++m) acc[m] = f32x4{0.f, 0.f, 0.f, 0.f};
    const short* ep = eB + (size_t)(j * 8192 + rowbase + lr) * 128;
    #pragma unroll
    for (int ks = 0; ks < 4; ++ks) {
      short8 a = *(const short8*)(ep + ks * 32 + kg * 8);
      #pragma unroll
      for (int m = 0; m < 8; ++m) {
        short8 b = *(const short8*)(&BW[(m * 16 + lr) * 136 + ks * 32 + kg * 8]);
        acc[m] = mfma16(a, b, acc[m]);
      }
    }
    #pragma unroll
    for (int m = 0; m < 8; ++m)
      #pragma unroll
      for (int r = 0; r < 4; ++r) {
        float x = acc[m][r] + bvv[m];
        Sacc[m][r] += (x > 0.f ? x : 0.01f * x);
      }
  }
  #pragma unroll
  for (int r = 0; r < 4; ++r) {
    short8 pkt;
    #pragma unroll
    for (int m = 0; m < 8; ++m) pkt[m] = f2bf(Sacc[m][r]);
    *(short8*)(SB + (size_t)(l * 8192 + rowbase + kg * 4 + r) * 128 + lr * 8) = pkt;
  }
}

// ---- K3: fused 17-chunk GEMM, 256 rows/block, 8 waves, agent->XCD pinned.
//      h = relu(sum_l (S_l - v_{l,i})@W1_l + e@W1e + b1); out = h.W2 + b2.
//      launch_bounds(512,2): VGPR cap 256 (R5's cap-128 spill fix).
//      Even chunks: B-fragment read once, feeds both s-subtiles (vacc[2][8]).
__global__ __launch_bounds__(512, 2) void k3_f(const short* __restrict__ eB,
                                               const short* __restrict__ SB,
                                               const short* __restrict__ WvP,
                                               const short* __restrict__ W1P,
                                               const float* __restrict__ bv,
                                               const float* __restrict__ b1,
                                               const float* __restrict__ W2,
                                               const float* __restrict__ b2,
                                               float* __restrict__ out) {
  __shared__ __align__(16) short BW[2][128 * 128];  // 64 KB dbuf
  __shared__ __align__(16) short VB[8][8 * 128];    // 16 KB, per-wave half-slices
  const int bid = blockIdx.x;
  const int i = bid & 7;        // agent -> XCD pinning (round-robin dispatch)
  const int btile = bid >> 3;   // 32 btiles x 256 rows
  const int tid = threadIdx.x;
  const int lane = tid & 63, wave = tid >> 6, lr = lane & 15, kg = lane >> 4;
  const int lr8 = lane & 7;
  const int rowbase = btile * 256 + wave * 32;
  const short* w1 = W1P + (size_t)i * 147456;
  short* vb = VB[wave];

#define STAGE_WV(buf, l)                                                       \
  {                                                                            \
    _Pragma("unroll") for (int t = 0; t < 4; ++t) {                            \
      int G = t * 512 + tid;                                                   \
      int cG = G >> 4, gl = G & 15;                                            \
      async_copy16((buf) + (t * 512 + wave * 64) * 8,                          \
                   WvP + (l) * 16384 + cG * 128 + ((gl ^ (cG & 7)) << 3));     \
    }                                                                          \
  }
#define STAGE_W1(buf, koff)                                                    \
  {                                                                            \
    _Pragma("unroll") for (int t = 0; t < 4; ++t) {                            \
      int G = t * 512 + tid;                                                   \
      int cG = G >> 4, gl = G & 15;                                            \
      async_copy16((buf) + (t * 512 + wave * 64) * 8,                          \
                   w1 + cG * 1152 + (koff) + ((gl ^ (cG & 7)) << 3));          \
    }                                                                          \
  }

  short8 ea[2][4];
  #pragma unroll
  for (int s = 0; s < 2; ++s)
    #pragma unroll
    for (int ks = 0; ks < 4; ++ks)
      ea[s][ks] = *(const short8*)(
          eB + (size_t)(i * 8192 + rowbase + s * 16 + lr) * 128 + (ks * 4 + kg) * 8);

  // SB prefetch registers (head l=0 loaded in prologue)
  short8 svp[2][4];
  #pragma unroll
  for (int s = 0; s < 2; ++s)
    #pragma unroll
    for (int r = 0; r < 4; ++r)
      svp[s][r] = *(const short8*)(
          SB + (size_t)(rowbase + s * 16 + kg * 4 + r) * 128 + lr * 8);

  f32x4 hacc[2][8];
  #pragma unroll
  for (int s = 0; s < 2; ++s)
    #pragma unroll
    for (int m = 0; m < 8; ++m) hacc[s][m] = f32x4{0.f, 0.f, 0.f, 0.f};
  short8 aa[2][4];

  STAGE_WV(BW[0], 0);
  for (int c = 0; c < 17; ++c) {
    __syncthreads();  // stage(c) drained; BW[(c+1)&1] free
    if (c < 16) {
      int nc = c + 1;
      if (nc == 16) { STAGE_W1(BW[0], 1024); }
      else if (nc & 1) { STAGE_W1(BW[1], (nc >> 1) * 128); }
      else { STAGE_WV(BW[0], nc >> 1); }
    }
    const short* bw = BW[c & 1];
    if (c == 16) {  // + e @ W1e
      #pragma unroll
      for (int ks = 0; ks < 4; ++ks)
        #pragma unroll
        for (int m = 0; m < 8; ++m) {
          short8 b = *(const short8*)(bw + (m * 16 + lr) * 128 +
                                      (((ks * 4 + kg) ^ lr8) << 3));
          hacc[0][m] = mfma16(ea[0][ks], b, hacc[0][m]);
          hacc[1][m] = mfma16(ea[1][ks], b, hacc[1][m]);
        }
    } else if (c & 1) {  // W1_l: hacc += (S-v) @ W1_l
      #pragma unroll
      for (int ks = 0; ks < 4; ++ks)
        #pragma unroll
        for (int m = 0; m < 8; ++m) {
          short8 b = *(const short8*)(bw + (m * 16 + lr) * 128 +
                                      (((ks * 4 + kg) ^ lr8) << 3));
          hacc[0][m] = mfma16(aa[0][ks], b, hacc[0][m]);
          hacc[1][m] = mfma16(aa[1][ks], b, hacc[1][m]);
        }
    } else {  // Wv_l: aa = S_l - leaky(e @ Wv_l + bv_l), via VB round-trip
      const int l = c >> 1;
      float bvv[8];
      #pragma unroll
      for (int m = 0; m < 8; ++m) bvv[m] = bv[l * 128 + m * 16 + lr];
      // v-MFMA with B-fragment read once for both s-subtiles
      f32x4 vacc[2][8];
      #pragma unroll
      for (int s = 0; s < 2; ++s)
        #pragma unroll
        for (int m = 0; m < 8; ++m) vacc[s][m] = f32x4{0.f, 0.f, 0.f, 0.f};
      #pragma unroll
      for (int ks = 0; ks < 4; ++ks)
        #pragma unroll
        for (int m = 0; m < 8; ++m) {
          short8 b = *(const short8*)(bw + (m * 16 + lr) * 128 +
                                      (((ks * 4 + kg) ^ lr8) << 3));
          vacc[0][m] = mfma16(ea[0][ks], b, vacc[0][m]);
          vacc[1][m] = mfma16(ea[1][ks], b, vacc[1][m]);
        }
      #pragma unroll
      for (int s = 0; s < 2; ++s) {
        short8 pkt[4];
        #pragma unroll
        for (int r = 0; r < 4; ++r)
          #pragma unroll
          for (int m = 0; m < 8; ++m) {
            float x = vacc[s][m][r] + bvv[m];
            x = (x > 0.f) ? x : 0.01f * x;   // leaky_relu
            pkt[r][m] = f2bf(bf2f(svp[s][r][m]) - x);
          }
        // C->A via 2KB/wave VB in two row-halves (exec-masked):
        // half p: lanes kg in {2p,2p+1} write local rows [0,8); lanes with
        // lr in [8p,8p+8) read their 4 A-fragments. Same-wave DS ordering
        // (compiler lgkmcnt) keeps write->read and half-reuse safe.
        #pragma unroll
        for (int p = 0; p < 2; ++p) {
          if ((kg >> 1) == p) {
            #pragma unroll
            for (int r = 0; r < 4; ++r) {
              int rl = (kg & 1) * 4 + r;
              *(short8*)(vb + rl * 128 + ((lr ^ rl) << 3)) = pkt[r];
            }
          }
          if ((lr >> 3) == p) {
            int rl = lr & 7;
            #pragma unroll
            for (int ks = 0; ks < 4; ++ks)
              aa[s][ks] = *(const short8*)(vb + rl * 128 +
                                           (((ks * 4 + kg) ^ rl) << 3));
          }
        }
      }
      // prefetch next head's SB operand (consumed at chunk c+2)
      if (l < 7) {
        #pragma unroll
        for (int s = 0; s < 2; ++s)
          #pragma unroll
          for (int r = 0; r < 4; ++r)
            svp[s][r] = *(const short8*)(
                SB + (size_t)((l + 1) * 8192 + rowbase + s * 16 + kg * 4 + r) * 128 +
                lr * 8);
      }
    }
  }
#undef STAGE_WV
#undef STAGE_W1

  // epilogue: h = relu(hacc + b1); out = h . W2 + b2
  #pragma unroll
  for (int s = 0; s < 2; ++s) {
    float sacc[4] = {0.f, 0.f, 0.f, 0.f};
    #pragma unroll
    for (int m = 0; m < 8; ++m) {
      int col = m * 16 + lr;
      float b1v = b1[i * 128 + col];
      float w2v = W2[i * 128 + col];
      #pragma unroll
      for (int r = 0; r < 4; ++r) {
        float h = hacc[s][m][r] + b1v;
        h = h > 0.f ? h : 0.f;
        sacc[r] += h * w2v;
      }
    }
    #pragma unroll
    for (int r = 0; r < 4; ++r) {
      float v = sacc[r];
      v += __shfl_xor(v, 1);
      v += __shfl_xor(v, 2);
      v += __shfl_xor(v, 4);
      v += __shfl_xor(v, 8);
      if (lr == 0)
        out[i * 8192 + rowbase + s * 16 + kg * 4 + r] = v + b2[i];
    }
  }
}

extern "C" void kernel_launch(void* const* d_in, const int* in_sizes, int n_in,
                              void* d_out, int out_size, void* d_ws, size_t ws_size,
                              hipStream_t stream) {
  const float* obs = (const float*)d_in[0];
  const float* act = (const float*)d_in[1];
  const float* Wg  = (const float*)d_in[2];
  const float* bg  = (const float*)d_in[3];
  // d_in[4..7] = Wq,bq,Wk,bk: dead (softmax over singleton axis == 1)
  const float* Wv  = (const float*)d_in[8];
  const float* bv  = (const float*)d_in[9];
  const float* W1  = (const float*)d_in[10];
  const float* b1  = (const float*)d_in[11];
  const float* W2  = (const float*)d_in[12];
  const float* b2  = (const float*)d_in[13];
  float* out = (float*)d_out;

  // workspace (bf16 shorts): eB 8.4M, SB 8.4M, WgT 163840, WvP 131072, W1P 1179648
  short* eB  = (short*)d_ws;
  short* SB  = eB + (size_t)8 * 8192 * 128;
  short* WgT = SB + (size_t)8 * 8192 * 128;
  short* WvP = WgT + 163840;
  short* W1P = WvP + 131072;

  k0_tr<<<720, 256, 0, stream>>>(Wg, Wv, W1, WgT, WvP, W1P);
  k1_e<<<dim3(128, 8), 256, 0, stream>>>(obs, act, WgT, bg, eB);
  k2_S<<<dim3(128, 8), 256, 0, stream>>>(eB, WvP, bv, SB);
  k3_f<<<256, 512, 0, stream>>>(eB, SB, WvP, W1P, bv, b1, W2, b2, out);
}

// Round 7
// 111.685 us; speedup vs baseline: 2.2066x; 2.1712x over previous
//
#include <hip/hip_runtime.h>

#define DEV static __device__ __forceinline__

typedef __attribute__((ext_vector_type(8))) short short8;
typedef __attribute__((ext_vector_type(8))) __bf16 bf16x8;
typedef __attribute__((ext_vector_type(4))) float f32x4;

// N=8 agents, B=8192, OBS=128, ACT=32, D=160, E=128, L=8
//
// pi-layout: within each 128-wide k-chunk, position p = 8*g + m holds actual
// k = 16*m + g. Applied consistently to eB, SB, WvP, W1P so MFMA operand
// elements pair correctly; benefit: a lane's 8 C-layout accumulator values
// (cols 16m+lr, m=0..7) form one contiguous 16B granule at (row, granule=lr).

DEV short f2bf(float f) { return __builtin_bit_cast(short, (__bf16)f); }
DEV float bf2f(short h) {
  unsigned u = ((unsigned)(unsigned short)h) << 16;
  return __builtin_bit_cast(float, u);
}
DEV f32x4 mfma16(short8 a, short8 b, f32x4 c) {
  return __builtin_amdgcn_mfma_f32_16x16x32_bf16(
      __builtin_bit_cast(bf16x8, a), __builtin_bit_cast(bf16x8, b), c, 0, 0, 0);
}
DEV void async_copy16(short* lds, const short* g) {
  __builtin_amdgcn_global_load_lds(
      (const __attribute__((address_space(1))) void*)g,
      (__attribute__((address_space(3))) void*)lds, 16, 0, 0);
}

template <int GPC, int SRC_STRIDE, int LDS_STRIDE>
DEV void stage_bt(short* lds, const short* src, int tid) {
  constexpr int TOTAL = 128 * GPC;
  #pragma unroll
  for (int g0 = 0; g0 < TOTAL; g0 += 256) {
    int g = g0 + tid;
    int c = g / GPC, kg = g % GPC;
    *(short8*)(lds + c * LDS_STRIDE + kg * 8) =
        *(const short8*)(src + c * SRC_STRIDE + kg * 8);
  }
}

// ---- K0: weights fp32 [K][128] -> bf16 [128][K]; Wv/W1 in pi-k order.
//      c-fastest lane mapping so the fp32 source reads coalesce. ------------
__global__ __launch_bounds__(256) void k0_tr(const float* __restrict__ Wg,
                                             const float* __restrict__ Wv,
                                             const float* __restrict__ W1,
                                             short* __restrict__ WgT,
                                             short* __restrict__ WvP,
                                             short* __restrict__ W1P) {
  int g = blockIdx.x * 256 + threadIdx.x;  // 184320 granules total
  short8 o;
  if (g < 20480) {  // Wg: 8 x 20kg x 128c, K=160, natural k
    int n = g / 2560, rem = g % 2560;
    int c = rem & 127, kg = rem >> 7;
    const float* src = Wg + n * 20480;
    #pragma unroll
    for (int j = 0; j < 8; ++j) o[j] = f2bf(src[(size_t)(kg * 8 + j) * 128 + c]);
    *(short8*)(WgT + n * 20480 + c * 160 + kg * 8) = o;
  } else if (g < 36864) {  // Wv: 8 x 16kg x 128c, K=128, pi order
    int g2 = g - 20480;
    int n = g2 >> 11, rem = g2 & 2047;
    int c = rem & 127, kg = rem >> 7;
    const float* src = Wv + n * 16384;
    #pragma unroll
    for (int j = 0; j < 8; ++j) o[j] = f2bf(src[(size_t)(16 * j + kg) * 128 + c]);
    *(short8*)(WvP + n * 16384 + c * 128 + kg * 8) = o;
  } else {  // W1: 8 x 144kg x 128c, K=1152, pi order within each 128-chunk
    int g3 = g - 36864;
    int n = g3 / 18432, rem = g3 % 18432;
    int c = rem & 127, kg = rem >> 7;
    int chunk = kg >> 4, kl = kg & 15;
    const float* src = W1 + (size_t)n * 147456;
    #pragma unroll
    for (int j = 0; j < 8; ++j)
      o[j] = f2bf(src[(size_t)(chunk * 128 + 16 * j + kl) * 128 + c]);
    *(short8*)(W1P + (size_t)n * 147456 + c * 1152 + kg * 8) = o;
  }
}

// ---- K1: e = relu(oa @ Wg + bg) -> bf16, pi-packed granule stores ----------
__global__ __launch_bounds__(256) void k1_e(const float* __restrict__ obs,
                                            const float* __restrict__ act,
                                            const short* __restrict__ WgT,
                                            const float* __restrict__ bg,
                                            short* __restrict__ eB) {
  __shared__ __align__(16) short BW[128 * 168];
  const int btile = blockIdx.x, n = blockIdx.y, tid = threadIdx.x;
  stage_bt<20, 160, 168>(BW, WgT + n * 20480, tid);
  __syncthreads();
  const int lane = tid & 63, wave = tid >> 6, lr = lane & 15, kg = lane >> 4;
  const int rowbase = btile * 64 + wave * 16;
  f32x4 acc[8];
  #pragma unroll
  for (int m = 0; m < 8; ++m) acc[m] = f32x4{0.f, 0.f, 0.f, 0.f};
  const float* obsp = obs + (size_t)(n * 8192 + rowbase + lr) * 128;
  const float* actp = act + (size_t)(n * 8192 + rowbase + lr) * 32;
  #pragma unroll
  for (int ks = 0; ks < 5; ++ks) {
    const float* ap = (ks < 4) ? (obsp + ks * 32 + kg * 8) : (actp + kg * 8);
    float4 p0 = *(const float4*)ap;
    float4 p1 = *(const float4*)(ap + 4);
    short8 a;
    a[0] = f2bf(p0.x); a[1] = f2bf(p0.y); a[2] = f2bf(p0.z); a[3] = f2bf(p0.w);
    a[4] = f2bf(p1.x); a[5] = f2bf(p1.y); a[6] = f2bf(p1.z); a[7] = f2bf(p1.w);
    #pragma unroll
    for (int m = 0; m < 8; ++m) {
      short8 b = *(const short8*)(&BW[(m * 16 + lr) * 168 + ks * 32 + kg * 8]);
      acc[m] = mfma16(a, b, acc[m]);
    }
  }
  float bgv[8];
  #pragma unroll
  for (int m = 0; m < 8; ++m) bgv[m] = bg[n * 128 + m * 16 + lr];
  #pragma unroll
  for (int r = 0; r < 4; ++r) {
    short8 pkt;
    #pragma unroll
    for (int m = 0; m < 8; ++m) {
      float x = acc[m][r] + bgv[m];
      pkt[m] = f2bf(x > 0.f ? x : 0.f);
    }
    *(short8*)(eB + (size_t)(n * 8192 + rowbase + kg * 4 + r) * 128 + lr * 8) = pkt;
  }
}

// ---- K2: S[l] = sum_j leaky(e[j] @ Wv[l] + bv[l]) -> bf16, pi-packed -------
__global__ __launch_bounds__(256) void k2_S(const short* __restrict__ eB,
                                            const short* __restrict__ WvP,
                                            const float* __restrict__ bv,
                                            short* __restrict__ SB) {
  __shared__ __align__(16) short BW[128 * 136];
  const int btile = blockIdx.x, l = blockIdx.y, tid = threadIdx.x;
  stage_bt<16, 128, 136>(BW, WvP + l * 16384, tid);
  __syncthreads();
  const int lane = tid & 63, wave = tid >> 6, lr = lane & 15, kg = lane >> 4;
  const int rowbase = btile * 64 + wave * 16;
  f32x4 Sacc[8];
  #pragma unroll
  for (int m = 0; m < 8; ++m) Sacc[m] = f32x4{0.f, 0.f, 0.f, 0.f};
  float bvv[8];
  #pragma unroll
  for (int m = 0; m < 8; ++m) bvv[m] = bv[l * 128 + m * 16 + lr];
  for (int j = 0; j < 8; ++j) {
    f32x4 acc[8];
    #pragma unroll
    for (int m = 0; m < 8; ++m) acc[m] = f32x4{0.f, 0.f, 0.f, 0.f};
    const short* ep = eB + (size_t)(j * 8192 + rowbase + lr) * 128;
    #pragma unroll
    for (int ks = 0; ks < 4; ++ks) {
      short8 a = *(const short8*)(ep + ks * 32 + kg * 8);
      #pragma unroll
      for (int m = 0; m < 8; ++m) {
        short8 b = *(const short8*)(&BW[(m * 16 + lr) * 136 + ks * 32 + kg * 8]);
        acc[m] = mfma16(a, b, acc[m]);
      }
    }
    #pragma unroll
    for (int m = 0; m < 8; ++m)
      #pragma unroll
      for (int r = 0; r < 4; ++r) {
        float x = acc[m][r] + bvv[m];
        Sacc[m][r] += (x > 0.f ? x : 0.01f * x);
      }
  }
  #pragma unroll
  for (int r = 0; r < 4; ++r) {
    short8 pkt;
    #pragma unroll
    for (int m = 0; m < 8; ++m) pkt[m] = f2bf(Sacc[m][r]);
    *(short8*)(SB + (size_t)(l * 8192 + rowbase + kg * 4 + r) * 128 + lr * 8) = pkt;
  }
}

// ---- K3: fused 17-chunk GEMM, 256 rows/block, 8 waves, agent->XCD pinned.
//      h = relu(sum_l (S_l - v_{l,i})@W1_l + e@W1e + b1); out = h.W2 + b2.
//      Arch-register diet (R6 spill fix): no persistent SB prefetch regs
//      (sv loaded at even-chunk top, L3-resident), per-s vacc[8].
__global__ __launch_bounds__(512, 2) void k3_f(const short* __restrict__ eB,
                                               const short* __restrict__ SB,
                                               const short* __restrict__ WvP,
                                               const short* __restrict__ W1P,
                                               const float* __restrict__ bv,
                                               const float* __restrict__ b1,
                                               const float* __restrict__ W2,
                                               const float* __restrict__ b2,
                                               float* __restrict__ out) {
  __shared__ __align__(16) short BW[2][128 * 128];  // 64 KB dbuf
  __shared__ __align__(16) short VB[8][8 * 128];    // 16 KB, per-wave half-slices
  const int bid = blockIdx.x;
  const int i = bid & 7;        // agent -> XCD pinning (round-robin dispatch)
  const int btile = bid >> 3;   // 32 btiles x 256 rows
  const int tid = threadIdx.x;
  const int lane = tid & 63, wave = tid >> 6, lr = lane & 15, kg = lane >> 4;
  const int lr8 = lane & 7;
  const int rowbase = btile * 256 + wave * 32;
  const short* w1 = W1P + (size_t)i * 147456;
  short* vb = VB[wave];

#define STAGE_WV(buf, l)                                                       \
  {                                                                            \
    _Pragma("unroll") for (int t = 0; t < 4; ++t) {                            \
      int G = t * 512 + tid;                                                   \
      int cG = G >> 4, gl = G & 15;                                            \
      async_copy16((buf) + (t * 512 + wave * 64) * 8,                          \
                   WvP + (l) * 16384 + cG * 128 + ((gl ^ (cG & 7)) << 3));     \
    }                                                                          \
  }
#define STAGE_W1(buf, koff)                                                    \
  {                                                                            \
    _Pragma("unroll") for (int t = 0; t < 4; ++t) {                            \
      int G = t * 512 + tid;                                                   \
      int cG = G >> 4, gl = G & 15;                                            \
      async_copy16((buf) + (t * 512 + wave * 64) * 8,                          \
                   w1 + cG * 1152 + (koff) + ((gl ^ (cG & 7)) << 3));          \
    }                                                                          \
  }

  short8 ea[2][4];
  #pragma unroll
  for (int s = 0; s < 2; ++s)
    #pragma unroll
    for (int ks = 0; ks < 4; ++ks)
      ea[s][ks] = *(const short8*)(
          eB + (size_t)(i * 8192 + rowbase + s * 16 + lr) * 128 + (ks * 4 + kg) * 8);

  f32x4 hacc[2][8];
  #pragma unroll
  for (int s = 0; s < 2; ++s)
    #pragma unroll
    for (int m = 0; m < 8; ++m) hacc[s][m] = f32x4{0.f, 0.f, 0.f, 0.f};
  short8 aa[2][4];

  STAGE_WV(BW[0], 0);
  for (int c = 0; c < 17; ++c) {
    __syncthreads();  // stage(c) drained; BW[(c+1)&1] free
    if (c < 16) {
      int nc = c + 1;
      if (nc == 16) { STAGE_W1(BW[0], 1024); }
      else if (nc & 1) { STAGE_W1(BW[1], (nc >> 1) * 128); }
      else { STAGE_WV(BW[0], nc >> 1); }
    }
    const short* bw = BW[c & 1];
    if (c == 16) {  // + e @ W1e
      #pragma unroll
      for (int ks = 0; ks < 4; ++ks)
        #pragma unroll
        for (int m = 0; m < 8; ++m) {
          short8 b = *(const short8*)(bw + (m * 16 + lr) * 128 +
                                      (((ks * 4 + kg) ^ lr8) << 3));
          hacc[0][m] = mfma16(ea[0][ks], b, hacc[0][m]);
          hacc[1][m] = mfma16(ea[1][ks], b, hacc[1][m]);
        }
    } else if (c & 1) {  // W1_l: hacc += (S-v) @ W1_l
      #pragma unroll
      for (int ks = 0; ks < 4; ++ks)
        #pragma unroll
        for (int m = 0; m < 8; ++m) {
          short8 b = *(const short8*)(bw + (m * 16 + lr) * 128 +
                                      (((ks * 4 + kg) ^ lr8) << 3));
          hacc[0][m] = mfma16(aa[0][ks], b, hacc[0][m]);
          hacc[1][m] = mfma16(aa[1][ks], b, hacc[1][m]);
        }
    } else {  // Wv_l: aa = S_l - leaky(e @ Wv_l + bv_l), via VB round-trip
      const int l = c >> 1;
      float bvv[8];
      #pragma unroll
      for (int m = 0; m < 8; ++m) bvv[m] = bv[l * 128 + m * 16 + lr];
      #pragma unroll
      for (int s = 0; s < 2; ++s) {
        // sv loads issued up front; latency covered by the 32 v-MFMAs below
        short8 sv[4];
        #pragma unroll
        for (int r = 0; r < 4; ++r)
          sv[r] = *(const short8*)(
              SB + (size_t)(l * 8192 + rowbase + s * 16 + kg * 4 + r) * 128 + lr * 8);
        f32x4 vacc[8];
        #pragma unroll
        for (int m = 0; m < 8; ++m) vacc[m] = f32x4{0.f, 0.f, 0.f, 0.f};
        #pragma unroll
        for (int ks = 0; ks < 4; ++ks)
          #pragma unroll
          for (int m = 0; m < 8; ++m) {
            short8 b = *(const short8*)(bw + (m * 16 + lr) * 128 +
                                        (((ks * 4 + kg) ^ lr8) << 3));
            vacc[m] = mfma16(ea[s][ks], b, vacc[m]);
          }
        short8 pkt[4];
        #pragma unroll
        for (int r = 0; r < 4; ++r)
          #pragma unroll
          for (int m = 0; m < 8; ++m) {
            float x = vacc[m][r] + bvv[m];
            x = (x > 0.f) ? x : 0.01f * x;   // leaky_relu
            pkt[r][m] = f2bf(bf2f(sv[r][m]) - x);
          }
        // C->A via 2KB/wave VB in two row-halves (exec-masked):
        // half p: lanes kg in {2p,2p+1} write local rows [0,8); lanes with
        // lr in [8p,8p+8) read their 4 A-fragments. Same-wave DS ordering
        // (compiler lgkmcnt) keeps write->read and half-reuse safe.
        #pragma unroll
        for (int p = 0; p < 2; ++p) {
          if ((kg >> 1) == p) {
            #pragma unroll
            for (int r = 0; r < 4; ++r) {
              int rl = (kg & 1) * 4 + r;
              *(short8*)(vb + rl * 128 + ((lr ^ rl) << 3)) = pkt[r];
            }
          }
          if ((lr >> 3) == p) {
            int rl = lr & 7;
            #pragma unroll
            for (int ks = 0; ks < 4; ++ks)
              aa[s][ks] = *(const short8*)(vb + rl * 128 +
                                           (((ks * 4 + kg) ^ rl) << 3));
          }
        }
      }
    }
  }
#undef STAGE_WV
#undef STAGE_W1

  // epilogue: h = relu(hacc + b1); out = h . W2 + b2
  #pragma unroll
  for (int s = 0; s < 2; ++s) {
    float sacc[4] = {0.f, 0.f, 0.f, 0.f};
    #pragma unroll
    for (int m = 0; m < 8; ++m) {
      int col = m * 16 + lr;
      float b1v = b1[i * 128 + col];
      float w2v = W2[i * 128 + col];
      #pragma unroll
      for (int r = 0; r < 4; ++r) {
        float h = hacc[s][m][r] + b1v;
        h = h > 0.f ? h : 0.f;
        sacc[r] += h * w2v;
      }
    }
    #pragma unroll
    for (int r = 0; r < 4; ++r) {
      float v = sacc[r];
      v += __shfl_xor(v, 1);
      v += __shfl_xor(v, 2);
      v += __shfl_xor(v, 4);
      v += __shfl_xor(v, 8);
      if (lr == 0)
        out[i * 8192 + rowbase + s * 16 + kg * 4 + r] = v + b2[i];
    }
  }
}

extern "C" void kernel_launch(void* const* d_in, const int* in_sizes, int n_in,
                              void* d_out, int out_size, void* d_ws, size_t ws_size,
                              hipStream_t stream) {
  const float* obs = (const float*)d_in[0];
  const float* act = (const float*)d_in[1];
  const float* Wg  = (const float*)d_in[2];
  const float* bg  = (const float*)d_in[3];
  // d_in[4..7] = Wq,bq,Wk,bk: dead (softmax over singleton axis == 1)
  const float* Wv  = (const float*)d_in[8];
  const float* bv  = (const float*)d_in[9];
  const float* W1  = (const float*)d_in[10];
  const float* b1  = (const float*)d_in[11];
  const float* W2  = (const float*)d_in[12];
  const float* b2  = (const float*)d_in[13];
  float* out = (float*)d_out;

  // workspace (bf16 shorts): eB 8.4M, SB 8.4M, WgT 163840, WvP 131072, W1P 1179648
  short* eB  = (short*)d_ws;
  short* SB  = eB + (size_t)8 * 8192 * 128;
  short* WgT = SB + (size_t)8 * 8192 * 128;
  short* WvP = WgT + 163840;
  short* W1P = WvP + 131072;

  k0_tr<<<720, 256, 0, stream>>>(Wg, Wv, W1, WgT, WvP, W1P);
  k1_e<<<dim3(128, 8), 256, 0, stream>>>(obs, act, WgT, bg, eB);
  k2_S<<<dim3(128, 8), 256, 0, stream>>>(eB, WvP, bv, SB);
  k3_f<<<256, 512, 0, stream>>>(eB, SB, WvP, W1P, bv, b1, W2, b2, out);
}